// Round 7
// baseline (220.861 us; speedup 1.0000x reference)
//
#include <hip/hip_runtime.h>

// Sinkhorn, B=8 N=1024 C=64, T=2, eps=0.1, 20 iters, scale=1e-3.
// Only batch 7 contributes (reference returns losses[-1]).
// u = 1/(K v), v = 1/(K^T u); loss = sum u_i K_ij v_j W_ij, W = -0.1*log K.
//
// Round 7: minimal-traffic epoch protocol. R4-R6 all plateaued at ~4.3us per
// cross-block exchange; suspect poll-traffic contention (R6 polled 8KB of
// tagged words from 65K threads every round). Now: plain packed u/v arrays +
// per-producer epoch flags (64 ints). One wave per block polls 64 ints with
// ONE sc0sc1 load/lane per round (16KB/round total, ~128x less traffic).
// Payload ordering: block's slice stores drain at __syncthreads (vmcnt ack =
// coherence point, validated bit-exact by R4/R6), then epoch flag store.
// Iteration cohort = 64 blocks; 256 builder blocks for softmax + K/KT.

typedef unsigned long long u64;

static constexpr int N  = 1024;
static constexpr int C  = 64;
static constexpr int NB = 256;   // launch width (phases 1-2)
static constexpr int NC = 64;    // iteration cohort

// float-offsets into ws (u64 arrays at even offsets)
static constexpr int WS_K    = 0;          // K  : 1024*1024 f32
static constexpr int WS_KT   = 1048576;    // KT : 1024*1024 f32
static constexpr int WS_U    = 2097152;    // u64[512]: packed pairs of u
static constexpr int WS_V    = 2098176;    // u64[512]: packed pairs of v
static constexpr int WS_MS   = 2099200;    // u64[64] tagged col max, y_s
static constexpr int WS_SS   = 2099328;    // u64[64] tagged col sum, y_s
static constexpr int WS_MT   = 2099456;    // u64[64] tagged col max, y_t
static constexpr int WS_ST   = 2099584;    // u64[64] tagged col sum, y_t
static constexpr int WS_P2   = 2099712;    // u64[64] tagged loss partials
static constexpr int WS_EPU  = 2099840;    // int[64] u epoch flags
static constexpr int WS_EPV  = 2099904;    // int[64] v epoch flags
static constexpr int WS_DF   = 2099968;    // int[256] phase-2 done flags

__device__ __forceinline__ void ast(float* p, float v) {
    __hip_atomic_store(p, v, __ATOMIC_RELAXED, __HIP_MEMORY_SCOPE_SYSTEM);
}
__device__ __forceinline__ void ast64(u64* p, u64 v) {
    __hip_atomic_store(p, v, __ATOMIC_RELAXED, __HIP_MEMORY_SCOPE_SYSTEM);
}
__device__ __forceinline__ u64 ald64(const u64* p) {
    return __hip_atomic_load(p, __ATOMIC_RELAXED, __HIP_MEMORY_SCOPE_SYSTEM);
}
__device__ __forceinline__ void asti(int* p, int v) {
    __hip_atomic_store(p, v, __ATOMIC_RELAXED, __HIP_MEMORY_SCOPE_SYSTEM);
}
__device__ __forceinline__ int aldi(const int* p) {
    return __hip_atomic_load(p, __ATOMIC_RELAXED, __HIP_MEMORY_SCOPE_SYSTEM);
}
__device__ __forceinline__ u64 pk(unsigned e, float f) {      // tag|float
    return ((u64)e << 32) | (u64)__float_as_uint(f);
}
__device__ __forceinline__ unsigned tg(u64 x) { return (unsigned)(x >> 32); }
__device__ __forceinline__ float    vl(u64 x) { return __uint_as_float((unsigned)x); }
__device__ __forceinline__ u64 pk2(float a, float b) {        // two floats
    return ((u64)__float_as_uint(b) << 32) | (u64)__float_as_uint(a);
}
__device__ __forceinline__ float p2lo(u64 x) { return __uint_as_float((unsigned)x); }
__device__ __forceinline__ float p2hi(u64 x) { return __uint_as_float((unsigned)(x >> 32)); }

__device__ __forceinline__ float wsum(float v) {
    #pragma unroll
    for (int o = 32; o > 0; o >>= 1) v += __shfl_down(v, o, 64);
    return v;
}
__device__ __forceinline__ float wmax(float v) {
    #pragma unroll
    for (int o = 32; o > 0; o >>= 1) v = fmaxf(v, __shfl_down(v, o, 64));
    return v;
}

__global__ void __launch_bounds__(256)
sink_k(const float* __restrict__ ysrc, const float* __restrict__ ytrc,
       float* __restrict__ out, float* __restrict__ ws)
{
    // sx 32*64=2048 | sy 32*68=2176 | kt 32*33=1056 -> 5280 floats (21.1 KB)
    __shared__ float smem[5280];
    const int tid  = threadIdx.x;
    const int bid  = blockIdx.x;
    const int wid  = tid >> 6;
    const int lane = tid & 63;
    u64* U64v = (u64*)(ws + WS_U);
    u64* V64v = (u64*)(ws + WS_V);
    u64* MS = (u64*)(ws + WS_MS);
    u64* SS = (u64*)(ws + WS_SS);
    u64* MT = (u64*)(ws + WS_MT);
    u64* ST = (u64*)(ws + WS_ST);
    u64* P2 = (u64*)(ws + WS_P2);
    int* EPU = (int*)(ws + WS_EPU);
    int* EPV = (int*)(ws + WS_EPV);
    int* DF  = (int*)(ws + WS_DF);
    float* K  = ws + WS_K;
    float* KT = ws + WS_KT;
    const float* ys7 = ysrc + 7 * N * C;
    const float* yt7 = ytrc + 7 * N * C;

    // cohort blocks pre-issue initial v = 1 (rows 16*bid..16*bid+15);
    // drained by the phase-2-end __syncthreads before EPV[bid]=1 is set.
    if (bid < NC && tid == 0) {
        const u64 one2 = pk2(1.0f, 1.0f);
        #pragma unroll
        for (int q = 0; q < 8; ++q) ast64(&V64v[bid * 8 + q], one2);
    }

    // ---- phase 1: per-column softmax stats (max, sum), batch 7 ----
    if (bid < 2 * C) {
        const float* src = (bid < C) ? ys7 : yt7;
        const int c = bid & (C - 1);
        float vals[4];
        float m = -1e30f;
        #pragma unroll
        for (int q = 0; q < 4; ++q) {
            vals[q] = src[(q * 256 + tid) * C + c] * 0.5f;   // y/T, T=2
            m = fmaxf(m, vals[q]);
        }
        m = wmax(m);
        if (lane == 0) smem[wid] = m;
        __syncthreads();
        m = fmaxf(fmaxf(smem[0], smem[1]), fmaxf(smem[2], smem[3]));
        float s = 0.f;
        #pragma unroll
        for (int q = 0; q < 4; ++q) s += expf(vals[q] - m);
        s = wsum(s);
        __syncthreads();
        if (lane == 0) smem[wid] = s;
        __syncthreads();
        s = smem[0] + smem[1] + smem[2] + smem[3];
        if (tid == 0) {
            u64* Mo = (bid < C) ? MS : MT;
            u64* So = (bid < C) ? SS : ST;
            ast64(&Mo[c], pk(1u, m));
            ast64(&So[c], pk(1u, s));
        }
        __syncthreads();          // smem reused in phase 2
    }

    // ---- phase 2: poll softmax stats, build K and KT (4 32x32 tiles/block)
    float mxs, isx, mys, isy;
    {
        const int c = tid & 63;
        u64 a0 = ald64(&MS[c]), a1 = ald64(&SS[c]);
        u64 a2 = ald64(&MT[c]), a3 = ald64(&ST[c]);
        int g = 0;
        while (tg(a0) != 1u || tg(a1) != 1u || tg(a2) != 1u || tg(a3) != 1u) {
            if (tg(a0) != 1u) a0 = ald64(&MS[c]);
            if (tg(a1) != 1u) a1 = ald64(&SS[c]);
            if (tg(a2) != 1u) a2 = ald64(&MT[c]);
            if (tg(a3) != 1u) a3 = ald64(&ST[c]);
            __builtin_amdgcn_s_sleep(1);
            if (++g > (1 << 22)) break;     // bailout: no hang
        }
        mxs = vl(a0); isx = 1.0f / vl(a1);
        mys = vl(a2); isy = 1.0f / vl(a3);
    }
    {
        float* sx = smem;          // [32][64]
        float* sy = smem + 2048;   // [32][68]
        float* kt = smem + 4224;   // [32][33]
        #pragma unroll 1
        for (int t = 0; t < 4; ++t) {
            const int tt = bid * 4 + t;
            const int ti = tt >> 5, tj = tt & 31;
            __syncthreads();
            // on-the-fly softmax: element k has column tid&63 == the c whose
            // (m,s) this thread polled -> bitwise-identical to materialized.
            for (int k = tid; k < 2048; k += 256)
                sx[k] = expf(ys7[ti * 2048 + k] * 0.5f - mxs) * isx;
            for (int k = tid; k < 2048; k += 256)
                sy[(k >> 6) * 68 + (k & 63)] =
                    expf(yt7[tj * 2048 + k] * 0.5f - mys) * isy;
            __syncthreads();
            float kv[4];
            #pragma unroll
            for (int q = 0; q < 4; ++q) {
                const int idx = q * 256 + tid;
                const int il = idx >> 5, jl = idx & 31;
                const float4* sx4 = (const float4*)(sx + il * 64);
                const float4* sy4 = (const float4*)(sy + jl * 68);
                float a = 0.f;
                #pragma unroll
                for (int c4 = 0; c4 < 16; ++c4) {
                    const float4 xa = sx4[c4], yb = sy4[c4];
                    a += fabsf(xa.x - yb.x) + fabsf(xa.y - yb.y)
                       + fabsf(xa.z - yb.z) + fabsf(xa.w - yb.w);
                }
                kv[q] = expf(-10.0f * a);                      // exp(-W/eps)
                ast(&K[(ti * 32 + il) * N + tj * 32 + jl], kv[q]);
            }
            __syncthreads();
            #pragma unroll
            for (int q = 0; q < 4; ++q) {
                const int idx = q * 256 + tid;
                kt[(idx >> 5) * 33 + (idx & 31)] = kv[q];
            }
            __syncthreads();
            #pragma unroll
            for (int q = 0; q < 4; ++q) {
                const int idx = q * 256 + tid;
                const int jl = idx >> 5, il = idx & 31;
                ast(&KT[(tj * 32 + jl) * N + ti * 32 + il], kt[il * 33 + jl]);
            }
        }
    }
    __syncthreads();               // vmcnt drain: K/KT (and cohort's v-ones)
    if (tid == 0) {                // are at the coherence point before flags
        asti(&DF[bid], 1);
        if (bid < NC) asti(&EPV[bid], 1);
    }
    if (bid >= NC) return;         // builders done; cohort continues

    // ---- phase 3 pre: wait for all 256 builder done-flags (one-time) ----
    {
        int g = 0;
        for (;;) {
            int f = aldi(&DF[wid * 64 + lane]);   // 4 waves x 64 = 256
            if (__ballot(f < 1) == 0ULL) break;
            __builtin_amdgcn_s_sleep(1);
            if (++g > (1 << 22)) break;
        }
    }
    __syncthreads();

    // ---- phase 3: 20 iterations; wave owns rows 4W..4W+3, W = bid*4+wid ----
    const int W = bid * 4 + wid;
    const float4* sv4 = (const float4*)smem;

    // stage: one wave polls the 64 epoch flags (1 sc0sc1 int load per lane
    // per round); then all threads bulk-read the packed vector into LDS.
    auto stage = [&](const u64* src64, int* epArr, int e) {
        if (wid == 0) {
            int g = 0;
            for (;;) {
                int f = aldi(&epArr[lane]);
                if (__ballot(f < e) == 0ULL) break;
                __builtin_amdgcn_s_sleep(1);
                if (++g > (1 << 22)) break;
            }
        }
        __syncthreads();
        u64 x0 = ald64(&src64[tid]);
        u64 x1 = ald64(&src64[tid + 256]);
        smem[2 * tid]     = p2lo(x0);
        smem[2 * tid + 1] = p2hi(x0);
        smem[2 * tid + 512]     = p2lo(x1);
        smem[2 * tid + 1 + 512] = p2hi(x1);
        __syncthreads();
    };

    float u_keep[4];
    #pragma unroll 1
    for (int it = 0; it < 20; ++it) {
        stage(V64v, EPV, it + 1);
        float r0, r1, r2, r3;
        {
            float acc[4];
            #pragma unroll
            for (int q = 0; q < 4; ++q) {
                const float4* Kr = (const float4*)(K + (size_t)(4 * W + q) * N);
                float a = 0.f;
                #pragma unroll
                for (int k = 0; k < 4; ++k) {
                    const int j = lane + 64 * k;
                    const float4 kk = Kr[j]; const float4 vv = sv4[j];
                    a += kk.x * vv.x + kk.y * vv.y + kk.z * vv.z + kk.w * vv.w;
                }
                acc[q] = wsum(a);
            }
            r0 = 1.0f / acc[0]; r1 = 1.0f / acc[1];
            r2 = 1.0f / acc[2]; r3 = 1.0f / acc[3];
            if (lane == 0) {
                ast64(&U64v[2 * W],     pk2(r0, r1));
                ast64(&U64v[2 * W + 1], pk2(r2, r3));
            }
            u_keep[0] = r0; u_keep[1] = r1; u_keep[2] = r2; u_keep[3] = r3;
        }
        __syncthreads();                       // drain u stores (all waves)
        if (tid == 0) asti(&EPU[bid], it + 1);
        stage(U64v, EPU, it + 1);
        {
            float acc[4];
            #pragma unroll
            for (int q = 0; q < 4; ++q) {
                const float4* Kr = (const float4*)(KT + (size_t)(4 * W + q) * N);
                float a = 0.f;
                #pragma unroll
                for (int k = 0; k < 4; ++k) {
                    const int j = lane + 64 * k;
                    const float4 kk = Kr[j]; const float4 uu = sv4[j];
                    a += kk.x * uu.x + kk.y * uu.y + kk.z * uu.z + kk.w * uu.w;
                }
                acc[q] = wsum(a);
            }
            if (lane == 0) {
                ast64(&V64v[2 * W],     pk2(1.0f / acc[0], 1.0f / acc[1]));
                ast64(&V64v[2 * W + 1], pk2(1.0f / acc[2], 1.0f / acc[3]));
            }
        }
        __syncthreads();                       // drain v stores
        if (tid == 0) asti(&EPV[bid], it + 2);
    }

    // ---- phase 4: partial[bid] over rows 4W..4W+3 of u_i K_ij v_j log K_ij
    {
        stage(V64v, EPV, 21);                  // final v
        float bsum = 0.f;
        #pragma unroll
        for (int q = 0; q < 4; ++q) {
            const float* Kr = K + (size_t)(4 * W + q) * N;
            float a = 0.f;
            for (int j = lane; j < N; j += 64) {
                const float kx = Kr[j];
                a += kx * smem[j] * logf(kx);
            }
            a = wsum(a);
            if (lane == 0) bsum += u_keep[q] * a;   // u_keep = u at it=19
        }
        if (lane == 0) smem[1028 + wid] = bsum;
        __syncthreads();
        if (tid == 0)
            ast64(&P2[bid], pk(1u, smem[1028] + smem[1029]
                                 + smem[1030] + smem[1031]));
    }

    // ---- phase 5: block 0 wave 0 polls 64 tagged partials -> out ----
    if (bid == 0 && wid == 0) {
        u64 x = ald64(&P2[lane]);
        int g = 0;
        while (tg(x) != 1u) {
            x = ald64(&P2[lane]);
            __builtin_amdgcn_s_sleep(1);
            if (++g > (1 << 22)) break;
        }
        float a = wsum(vl(x));
        if (lane == 0) out[0] = -1e-4f * a;    // 1e-3 * (-0.1)
    }
}

extern "C" void kernel_launch(void* const* d_in, const int* in_sizes, int n_in,
                              void* d_out, int out_size, void* d_ws, size_t ws_size,
                              hipStream_t stream) {
    const float* y_s = (const float*)d_in[0];
    const float* y_t = (const float*)d_in[1];
    float* out = (float*)d_out;
    float* ws  = (float*)d_ws;
    sink_k<<<dim3(NB), dim3(256), 0, stream>>>(y_s, y_t, out, ws);
}